// Round 7
// baseline (287.381 us; speedup 1.0000x reference)
//
#include <hip/hip_runtime.h>
#include <hip/hip_bf16.h>

typedef __hip_bfloat16 bf16;
typedef __attribute__((ext_vector_type(8))) short short8v;   // bf16x8 MFMA fragment
typedef __attribute__((ext_vector_type(4))) float f32x4;     // MFMA accumulator

#define NB   32
#define NTT  512
#define NJ   17
#define ND   128
#define NP   6
#define NH   4
#define NDH  32
#define NBT  (NB*NTT)        // 16384 frames
#define NG   4               // frames per group
#define NTOK (NG*NP)         // 24 tokens per group
#define NMT  2               // M-tiles
#define NTHR 512             // 8 waves
#define GRID 1024            // blocks
#define NITER ((NBT/NG)/GRID)   // 4 groups per block
#define TSTR 136             // bf16 row stride: 272B
#define YSTR 132             // y fp32 row stride

// ws layout: bf16 wgt[81920] | fp32 bc[384] @163840 | u32 mb[16384] @165376
#define WS_WP 0
#define WS_WC 16384
#define WS_WO 65536
#define WS_BC 163840
#define WS_MB 165376

// LDS arena offsets (bytes)
#define OFF_POOL 0            // [24][136] bf16
#define OFF_TOKP 6528         // [24][136] bf16
#define OFF_Q    13056        // [24][136] bf16 ; o overwrites q after PV
#define OFF_K    19584        // [24][136] bf16 ; dead after scores
#define OFF_V    26112        // [24][136] bf16 ; dead after PV
#define OFF_Y    19584        // [24][132] fp32 aliases k|v
#define OFF_PROB 32640        // 576 fp32
#define OFF_MU   34944
#define OFF_INV  35040
#define ARENA_SZ 35136

__device__ __forceinline__ float bf2f(unsigned short u) {
    return __uint_as_float(((unsigned)u) << 16);
}
__device__ __forceinline__ f32x4 MFMA(short8v a, short8v b, f32x4 c) {
    return __builtin_amdgcn_mfma_f32_16x16x32_bf16(a, b, c, 0, 0, 0);
}
__device__ __forceinline__ short8v ldB(const bf16* __restrict__ W, int nt, int ks, int lane) {
    return *reinterpret_cast<const short8v*>(W + (nt*16 + (lane & 15))*ND + ks*32 + ((lane >> 4) << 3));
}
__device__ __forceinline__ short8v ldsA(const bf16* __restrict__ s, int mt, int ks, int lane) {
    int row = mt*16 + (lane & 15);
    if (row >= NTOK) row = NTOK - 1;
    return *reinterpret_cast<const short8v*>(s + row*TSTR + ks*32 + ((lane >> 4) << 3));
}
// LDS-ordering barrier WITHOUT vmcnt drain: global prefetch loads stay in flight.
__device__ __forceinline__ void bsync() {
    asm volatile("s_waitcnt lgkmcnt(0)" ::: "memory");
    __builtin_amdgcn_s_barrier();
    asm volatile("" ::: "memory");
}

// ---- K0: fp32 -> bf16 conversion of Wp, Wo ----
extern "C" __global__ __launch_bounds__(256)
void wconv(const float* __restrict__ Wp, const float* __restrict__ Wo,
           bf16* __restrict__ ws) {
    int i = blockIdx.x*256 + threadIdx.x;     // 32768 total
    if (i < 16384) ws[WS_WP + i] = __float2bfloat16(Wp[i]);
    else           ws[WS_WO + (i - 16384)] = __float2bfloat16(Wo[i - 16384]);
}

// ---- K1: Wc = Win @ Wp (384x128) bf16, bc = Win @ bp + bin ----
extern "C" __global__ __launch_bounds__(128)
void wcomb(const float* __restrict__ Wp, const float* __restrict__ Wi,
           const float* __restrict__ bp, const float* __restrict__ bi,
           bf16* __restrict__ wc, float* __restrict__ bc) {
    __shared__ float s_red[128];
    const int n = blockIdx.x;          // 0..383
    const int k = threadIdx.x;         // 0..127
    float acc = 0.f;
    #pragma unroll 4
    for (int m = 0; m < 128; ++m)
        acc = fmaf(Wi[n*128+m], Wp[m*128+k], acc);
    wc[n*128+k] = __float2bfloat16(acc);
    s_red[k] = Wi[n*128+k]*bp[k];
    __syncthreads();
    #pragma unroll
    for (int s = 64; s > 0; s >>= 1) {
        if (k < s) s_red[k] += s_red[k+s];
        __syncthreads();
    }
    if (k == 0) bc[n] = s_red[0] + bi[n];
}

// ---- K2: per-frame mask bitmask ----
extern "C" __global__ __launch_bounds__(256)
void mconv(const float* __restrict__ mask, unsigned* __restrict__ mb) {
    int fr = blockIdx.x*256 + threadIdx.x;    // 16384 frames
    const float* m = mask + (long)fr*NJ;
    unsigned b = 0;
    #pragma unroll
    for (int j = 0; j < NJ; ++j)
        b |= (m[j] > 0.05f) ? (1u << j) : 0u;
    mb[fr] = b;
}

extern "C" __global__ __launch_bounds__(NTHR, 6)
void bpa_fused(const float* __restrict__ h_joint,
               const bf16* __restrict__ wgt, const float* __restrict__ bc,
               const unsigned* __restrict__ mbuf,
               const float* __restrict__ b_proj, const float* __restrict__ b_out,
               const float* __restrict__ ln_g,  const float* __restrict__ ln_b,
               float* __restrict__ out)
{
    __shared__ __align__(16) unsigned char s_arena[ARENA_SZ];
    bf16*  s_pool  = reinterpret_cast<bf16*>(s_arena + OFF_POOL);
    bf16*  s_tokp  = reinterpret_cast<bf16*>(s_arena + OFF_TOKP);
    bf16*  s_q     = reinterpret_cast<bf16*>(s_arena + OFF_Q);
    bf16*  s_k     = reinterpret_cast<bf16*>(s_arena + OFF_K);
    bf16*  s_v     = reinterpret_cast<bf16*>(s_arena + OFF_V);
    float* s_y     = reinterpret_cast<float*>(s_arena + OFF_Y);
    float* s_probs = reinterpret_cast<float*>(s_arena + OFF_PROB);
    float* s_mu    = reinterpret_cast<float*>(s_arena + OFF_MU);
    float* s_inv   = reinterpret_cast<float*>(s_arena + OFF_INV);

    const int tid  = threadIdx.x;
    const int lane = tid & 63;
    const int w    = tid >> 6;                          // wave 0..7
    const int f    = tid >> 7;                          // frame-in-group 0..3
    const int d    = tid & (ND-1);                      // column 0..127

    // Per-thread fixed source column for pooling; iteration step = GRID*NG frames.
    const long fr0   = (long)blockIdx.x * NG + f;
    const float* hb0 = h_joint + fr0*(long)(NJ*ND) + d;
    const long FSTEP = (long)GRID*NG;                   // 4096 frames
    const long HSTEP = FSTEP*(long)(NJ*ND);

    // Prefetch iteration 0 (HBM loads + mask word) into registers.
    float    hv[2][NJ];
    unsigned mbv[2];
    #pragma unroll
    for (int j = 0; j < NJ; ++j) hv[0][j] = hb0[j*ND];
    mbv[0] = mbuf[fr0];

    #pragma unroll
    for (int it = 0; it < NITER; ++it) {
        const long frame0 = (long)blockIdx.x*NG + (long)it*FSTEP;
        const int  cur = it & 1, nxt = (it + 1) & 1;

        // ---- Stage 1: pooling from prefetched registers -> s_pool ----
        {
            unsigned mb = mbv[cur];
            float t[NJ];
            #pragma unroll
            for (int j = 0; j < NJ; ++j)
                t[j] = (mb >> j & 1) ? hv[cur][j] : 0.f;
            float acc[NP];
            acc[0] = ((t[0]+t[1]) + (t[2]+t[3])) + t[4];
            acc[1] = (t[5]+t[6]) + (t[11]+t[12]);
            acc[2] = t[5]+t[7]+t[9];
            acc[3] = t[6]+t[8]+t[10];
            acc[4] = t[11]+t[13]+t[15];
            acc[5] = t[12]+t[14]+t[16];
            const unsigned pm[NP] = {0x1Fu, 0x1860u, 0x2A0u, 0x540u, 0xA800u, 0x15000u};
            #pragma unroll
            for (int p = 0; p < NP; ++p) {
                float cnt = (float)__popc(mb & pm[p]);
                s_pool[(f*NP+p)*TSTR + d] = __float2bfloat16(acc[p] / fmaxf(cnt, 1e-6f));
            }
        }
        // ---- Prefetch next group's h columns + mask (stays in flight across bsync) ----
        if (it + 1 < NITER) {
            const float* hn = hb0 + (long)(it+1)*HSTEP;
            #pragma unroll
            for (int j = 0; j < NJ; ++j) hv[nxt][j] = hn[j*ND];
            mbv[nxt] = mbuf[fr0 + (long)(it+1)*FSTEP];
        }
        bsync();   // B1

        // ---- Stage 2: tok = pool@Wp^T + bp ; qkv = pool@Wc^T + bc ----
        {
            short8v bwp[4];
            #pragma unroll
            for (int ks = 0; ks < 4; ++ks) bwp[ks] = ldB(wgt + WS_WP, w, ks, lane);
            f32x4 acc[NMT];
            acc[0] = (f32x4)(0.f); acc[1] = (f32x4)(0.f);
            #pragma unroll
            for (int ks = 0; ks < 4; ++ks)
                #pragma unroll
                for (int mt = 0; mt < NMT; ++mt)
                    acc[mt] = MFMA(ldsA(s_pool, mt, ks, lane), bwp[ks], acc[mt]);
            int col = w*16 + (lane & 15);
            float bv = b_proj[col];
            #pragma unroll
            for (int mt = 0; mt < NMT; ++mt)
                #pragma unroll
                for (int j = 0; j < 4; ++j) {
                    int row = mt*16 + ((lane >> 4) << 2) + j;
                    if (row < NTOK)
                        s_tokp[row*TSTR + col] = __float2bfloat16(acc[mt][j] + bv);
                }
        }
        #pragma unroll
        for (int t = 0; t < 3; ++t) {           // q, k, v from combined Wc
            int nt = t*8 + w;
            short8v bw[4];
            #pragma unroll
            for (int ks = 0; ks < 4; ++ks) bw[ks] = ldB(wgt + WS_WC, nt, ks, lane);
            f32x4 acc[NMT];
            acc[0] = (f32x4)(0.f); acc[1] = (f32x4)(0.f);
            #pragma unroll
            for (int ks = 0; ks < 4; ++ks)
                #pragma unroll
                for (int mt = 0; mt < NMT; ++mt)
                    acc[mt] = MFMA(ldsA(s_pool, mt, ks, lane), bw[ks], acc[mt]);
            bf16* dst = (t == 0) ? s_q : (t == 1) ? s_k : s_v;
            int lcol = w*16 + (lane & 15);
            float bv = bc[nt*16 + (lane & 15)];
            #pragma unroll
            for (int mt = 0; mt < NMT; ++mt)
                #pragma unroll
                for (int j = 0; j < 4; ++j) {
                    int row = mt*16 + ((lane >> 4) << 2) + j;
                    if (row < NTOK)
                        dst[row*TSTR + lcol] = __float2bfloat16(acc[mt][j] + bv);
                }
        }
        bsync();   // B2

        // ---- Stage 3: scores + softmax -> s_probs ----
        if (tid < NG*NH*NP) {   // 96 threads: (f, h, qi)
            int ff  = tid / (NH*NP);
            int rem = tid - ff*(NH*NP);
            int h   = rem / NP;
            int qi  = rem - h*NP;
            const bf16* qrow = s_q + (ff*NP+qi)*TSTR + h*NDH;
            float sc[NP];
            float mx = -1e30f;
            #pragma unroll
            for (int pk = 0; pk < NP; ++pk) {
                const bf16* krow = s_k + (ff*NP+pk)*TSTR + h*NDH;
                float s = 0.f;
                #pragma unroll
                for (int c = 0; c < NDH; c += 4) {
                    ushort4 uq = *reinterpret_cast<const ushort4*>(qrow + c);
                    ushort4 uk = *reinterpret_cast<const ushort4*>(krow + c);
                    s += bf2f(uq.x)*bf2f(uk.x) + bf2f(uq.y)*bf2f(uk.y)
                       + bf2f(uq.z)*bf2f(uk.z) + bf2f(uq.w)*bf2f(uk.w);
                }
                sc[pk] = s * 0.17677669529663688f;
                mx = fmaxf(mx, sc[pk]);
            }
            float den = 0.f, e[NP];
            #pragma unroll
            for (int pk = 0; pk < NP; ++pk) { e[pk] = expf(sc[pk]-mx); den += e[pk]; }
            float inv = 1.f/den;
            #pragma unroll
            for (int pk = 0; pk < NP; ++pk)
                s_probs[((ff*NH+h)*NP+qi)*NP + pk] = e[pk]*inv;
        }
        bsync();   // B3

        // ---- Stage 4: part_importance + o = w @ v (o over dead q) ----
        if (tid < NG*NP) {  // 24 threads
            int ff = tid / NP, pk = tid - ff*NP;
            float s = 0.f;
            #pragma unroll
            for (int h = 0; h < NH; ++h)
                #pragma unroll
                for (int q = 0; q < NP; ++q)
                    s += s_probs[((ff*NH+h)*NP+q)*NP + pk];
            out[(long)NBT*NP*ND + (frame0+ff)*NP + pk] = s * (1.f/24.f);
        }
        #pragma unroll
        for (int i = 0; i < (NTOK*ND)/NTHR; ++i) {   // 6 iters
            int idx = i*NTHR + tid;
            int token = idx >> 7;
            int dd = idx & (ND-1);
            int ff = token / NP, qi = token - ff*NP;
            int h = dd >> 5;
            const float* pr = s_probs + ((ff*NH+h)*NP+qi)*NP;
            float s = 0.f;
            #pragma unroll
            for (int pk = 0; pk < NP; ++pk) {
                float v = bf2f(reinterpret_cast<const unsigned short*>(s_v)[(ff*NP+pk)*TSTR + dd]);
                s += pr[pk]*v;
            }
            s_q[token*TSTR + dd] = __float2bfloat16(s);
        }
        bsync();   // B4

        // ---- Stage 5: y = o @ Wo^T + b_out + tok -> fp32 y over dead k|v ----
        {
            short8v bo[4];
            #pragma unroll
            for (int ks = 0; ks < 4; ++ks) bo[ks] = ldB(wgt + WS_WO, w, ks, lane);
            f32x4 acc[NMT];
            acc[0] = (f32x4)(0.f); acc[1] = (f32x4)(0.f);
            #pragma unroll
            for (int ks = 0; ks < 4; ++ks)
                #pragma unroll
                for (int mt = 0; mt < NMT; ++mt)
                    acc[mt] = MFMA(ldsA(s_q, mt, ks, lane), bo[ks], acc[mt]);
            int col = w*16 + (lane & 15);
            float bv = b_out[col];
            #pragma unroll
            for (int mt = 0; mt < NMT; ++mt)
                #pragma unroll
                for (int j = 0; j < 4; ++j) {
                    int row = mt*16 + ((lane >> 4) << 2) + j;
                    if (row < NTOK) {
                        float resid = bf2f(*reinterpret_cast<const unsigned short*>(&s_tokp[row*TSTR + col]));
                        s_y[row*YSTR + col] = acc[mt][j] + bv + resid;
                    }
                }
        }
        bsync();   // B5

        // ---- Stage 6: LayerNorm stats ----
        if (tid < NTOK*4) {   // 96 threads
            int token = tid >> 2, sub = tid & 3;
            const float* row = s_y + token*YSTR + sub*NDH;
            float s = 0.f, s2 = 0.f;
            #pragma unroll
            for (int j = 0; j < NDH; j += 4) {
                float4 v = *reinterpret_cast<const float4*>(row + j);
                s  += v.x + v.y + v.z + v.w;
                s2 += v.x*v.x + v.y*v.y + v.z*v.z + v.w*v.w;
            }
            s  += __shfl_xor(s, 1);  s  += __shfl_xor(s, 2);
            s2 += __shfl_xor(s2, 1); s2 += __shfl_xor(s2, 2);
            float mean = s * (1.f/128.f);
            float var  = s2 * (1.f/128.f) - mean*mean;
            if (sub == 0) {
                s_mu[token]  = mean;
                s_inv[token] = rsqrtf(var + 1e-5f);
            }
        }
        bsync();   // B6

        // ---- Stage 7: normalize + store ----
        #pragma unroll
        for (int i = 0; i < 2; ++i) {
            int idx4 = i*NTHR + tid;
            if (idx4 < NTOK*(ND/4)) {
                int token = idx4 >> 5;
                int dj = (idx4 & 31) << 2;
                float mean = s_mu[token], inv = s_inv[token];
                float4 v = *reinterpret_cast<const float4*>(s_y + token*YSTR + dj);
                float4 g = *reinterpret_cast<const float4*>(ln_g + dj);
                float4 b = *reinterpret_cast<const float4*>(ln_b + dj);
                float4 r;
                r.x = (v.x-mean)*inv*g.x + b.x;
                r.y = (v.y-mean)*inv*g.y + b.y;
                r.z = (v.z-mean)*inv*g.z + b.z;
                r.w = (v.w-mean)*inv*g.w + b.w;
                *reinterpret_cast<float4*>(out + (frame0*NP + token)*(long)ND + dj) = r;
            }
        }
        bsync();   // B7: s_y (k|v region) reads done before next iter's stage-2 writes
    }
}

extern "C" void kernel_launch(void* const* d_in, const int* in_sizes, int n_in,
                              void* d_out, int out_size, void* d_ws, size_t ws_size,
                              hipStream_t stream) {
    const float* h_joint = (const float*)d_in[0];
    const float* mask    = (const float*)d_in[1];
    const float* W_proj  = (const float*)d_in[2];
    const float* b_proj  = (const float*)d_in[3];
    const float* W_in    = (const float*)d_in[4];
    const float* b_in    = (const float*)d_in[5];
    const float* W_out   = (const float*)d_in[6];
    const float* b_out   = (const float*)d_in[7];
    const float* ln_g    = (const float*)d_in[8];
    const float* ln_b    = (const float*)d_in[9];
    float* out = (float*)d_out;
    bf16*     wgt  = (bf16*)d_ws;
    float*    bc   = (float*)((char*)d_ws + WS_BC);
    unsigned* mbuf = (unsigned*)((char*)d_ws + WS_MB);

    hipLaunchKernelGGL(wconv, dim3(32768/256), dim3(256), 0, stream,
                       W_proj, W_out, wgt);
    hipLaunchKernelGGL(wcomb, dim3(384), dim3(128), 0, stream,
                       W_proj, W_in, b_proj, b_in, wgt + WS_WC, bc);
    hipLaunchKernelGGL(mconv, dim3(NBT/256), dim3(256), 0, stream,
                       mask, mbuf);
    hipLaunchKernelGGL(bpa_fused, dim3(GRID), dim3(NTHR), 0, stream,
                       h_joint, wgt, bc, mbuf, b_proj, b_out, ln_g, ln_b, out);
}